// Round 6
// baseline (781.214 us; speedup 1.0000x reference)
//
#include <hip/hip_runtime.h>
#include <hip/hip_bf16.h>

// ---------------------------------------------------------------------------
// RoIHead fused persistent kernel, v2: 512 blocks x 256 threads (2 blocks/CU
// co-resident -> inter-block latency hiding preserved, unlike R5's 1/CU).
// Phases: roipool | gemm1 | reduce0 | gemm2 | reduce1+final, device-scope
// grid barriers (count=512). gemm body is byte-identical to R2's 87us kernel.
// ---------------------------------------------------------------------------

typedef __attribute__((ext_vector_type(8))) short bf16x8;
typedef __attribute__((ext_vector_type(4))) float f32x4;
typedef __attribute__((ext_vector_type(4))) short s16x4;

typedef const __attribute__((address_space(1))) void gvoid;
typedef __attribute__((address_space(3))) void lvoid;
#define GLD_LDS16(gp, lp) __builtin_amdgcn_global_load_lds((gvoid*)(gp), (lvoid*)(lp), 16, 0, 0)

#define WAITV8() { asm volatile("s_waitcnt vmcnt(8)" ::: "memory"); __builtin_amdgcn_sched_barrier(0); }
#define WAITV0() { asm volatile("s_waitcnt vmcnt(0)" ::: "memory"); __builtin_amdgcn_sched_barrier(0); }
#define BAR() { __builtin_amdgcn_sched_barrier(0); __builtin_amdgcn_s_barrier(); __builtin_amdgcn_sched_barrier(0); }

#define NBLK 512

__device__ int g_bar[8];   // loader-zeroed; exit handshake restores zeros

static __device__ __forceinline__ short f2bf(float f) {   // RNE f32->bf16
  unsigned u = __builtin_bit_cast(unsigned, f);
  u += 0x7fffu + ((u >> 16) & 1u);
  return (short)(u >> 16);
}

static __device__ __forceinline__ void gridbar(int idx) {
  __syncthreads();                     // drains vmcnt/lgkmcnt for whole block
  if (threadIdx.x == 0) {
    __threadfence();
    __hip_atomic_fetch_add(&g_bar[idx], 1, __ATOMIC_ACQ_REL, __HIP_MEMORY_SCOPE_AGENT);
    while (__hip_atomic_load(&g_bar[idx], __ATOMIC_ACQUIRE, __HIP_MEMORY_SCOPE_AGENT) < NBLK)
      __builtin_amdgcn_s_sleep(8);
    __threadfence();
  }
  __syncthreads();
}

// ---- one 128x64 output tile of part[s] = A[:,kc0:kc0+KC] @ B[kc0:+KC, n0:+64]
// 256 threads / 4 waves; BM=128, BN=64, BK=64; double-buffered 64KB LDS;
// counted vmcnt(8) pipeline. Identical structure to R2's gemm_kernel.
static __device__ void gemm_tile(const short* __restrict__ A, const float* __restrict__ B,
                                 float* __restrict__ part, int K, int KC, int steps,
                                 int tile, char* smem) {
  const int t = threadIdx.x;
  const int w = t >> 6, l = t & 63;
  const int s = tile & 7, nb = tile >> 3;  // s = bid&7: XCD keeps one A-chunk
  const int kc0 = s * KC;

  char* const bA[2] = { smem,         smem + 16384 };
  char* const bB[2] = { smem + 32768, smem + 49152 };

  int aoff[4], boff[4];
#pragma unroll
  for (int p = 0; p < 4; ++p) {
    int o = (p*256 + t) * 16;                 // linear LDS byte offset [0,16384)
    int oa = o ^ (((o >> 7) & 7) << 4);       // inverse A swizzle (involution)
    aoff[p] = (oa >> 7) * (K*2) + (oa & 127);
    int ob = o ^ (((o >> 11) & 1) << 6);      // inverse B swizzle (involution)
    boff[p] = (ob >> 8) * 16384 + (ob & 255);
  }
  const int r15 = l & 15, kh = l >> 4;
  const int xa = (r15 & 7) << 4;
  const int aoj0 = r15*128 + ((kh*16) ^ xa);
  const int aoj1 = r15*128 + ((64 + kh*16) ^ xa);
  const int bo0  = (kh*8*256 + (w*16 + r15)*4) ^ ((kh & 1) << 6);

  const char* Ak = (const char*)A + kc0*2;
  const char* Bk = (const char*)B + (size_t)kc0*16384 + (size_t)(nb*64)*4;

  f32x4 acc[8] = {};
  int cur = 0;
#pragma unroll
  for (int p = 0; p < 4; ++p) {
    GLD_LDS16(Ak + aoff[p], bA[0] + (p*256 + w*64)*16);
    GLD_LDS16(Bk + boff[p], bB[0] + (p*256 + w*64)*16);
  }
  Ak += 128; Bk += (size_t)64*16384;

  for (int st = 0; st < steps; ++st) {
    if (st + 1 < steps) {
      char* dA = bA[cur^1]; char* dB = bB[cur^1];
#pragma unroll
      for (int p = 0; p < 4; ++p) {
        GLD_LDS16(Ak + aoff[p], dA + (p*256 + w*64)*16);
        GLD_LDS16(Bk + boff[p], dB + (p*256 + w*64)*16);
      }
      Ak += 128; Bk += (size_t)64*16384;
      WAITV8();                    // my tile-st loads landed; next 8 in flight
    } else {
      WAITV0();
    }
    BAR();
    const char* lAb = bA[cur]; const char* lBb = bB[cur];
#pragma unroll
    for (int j = 0; j < 2; ++j) {
      const int ao = j ? aoj1 : aoj0;
      const int bo = j*8192 + bo0;
      float bf[8];
#pragma unroll
      for (int i2 = 0; i2 < 8; ++i2) bf[i2] = *(const float*)(lBb + bo + i2*256);
      bf16x8 bfrag;
#pragma unroll
      for (int i2 = 0; i2 < 8; ++i2) bfrag[i2] = f2bf(bf[i2]);
#pragma unroll
      for (int mf = 0; mf < 8; ++mf) {
        bf16x8 afrag = *(const bf16x8*)(lAb + mf*2048 + ao);
        acc[mf] = __builtin_amdgcn_mfma_f32_16x16x32_bf16(afrag, bfrag, acc[mf], 0, 0, 0);
      }
    }
    BAR();
    cur ^= 1;
  }
  // C/D: col = lane&15, row = (lane>>4)*4 + q
  const int n = nb*64 + w*16 + r15;
  float* prow = part + (size_t)s*524288 + n;
#pragma unroll
  for (int mf = 0; mf < 8; ++mf) {
    int m0 = mf*16 + kh*4;
#pragma unroll
    for (int q = 0; q < 4; ++q)
      prow[(m0 + q)*4096] = acc[mf][q];
  }
}

extern "C" __global__ void __launch_bounds__(256)
fused_roihead(const float* __restrict__ x, const float* __restrict__ rois,
              const float* __restrict__ W1, const float* __restrict__ b1,
              const float* __restrict__ W2, const float* __restrict__ b2,
              const float* __restrict__ Wloc, const float* __restrict__ bloc,
              const float* __restrict__ Wscore, const float* __restrict__ bscore,
              short* __restrict__ Apool, short* __restrict__ fc6,
              float* __restrict__ part, float* __restrict__ out) {
  __shared__ char smem[65536];
  const int t = threadIdx.x, b = blockIdx.x;

  // ---- Phase A: ROI pool -> Apool bf16 [128][25088]; 4096 units, 8/block ----
  {
    float* tl = (float*)smem;                   // [16][292] floats
    const int cl = t >> 4, i = t & 15;
    float* tlc = tl + cl*292;
    for (int u = 0; u < 8; ++u) {
      const int unit = u*NBLK + b;              // [0,4096)
      const int r = unit >> 5, cg = unit & 31;
      const int c = cg*16 + cl;
      const float y1 = rois[r*4+0], x1 = rois[r*4+1], y2 = rois[r*4+2], x2 = rois[r*4+3];
      const int h0 = (int)(y1*0.0625f), h1 = (int)(y2*0.0625f) + 1;
      const int w0 = (int)(x1*0.0625f), w1 = (int)(x2*0.0625f) + 1;
      const int Hh = h1-h0, Ww = w1-w0, n = Hh*Ww;   // <=17 each
      const float* xc = x + c*1850 + h0*50 + w0;
      for (int p = i; p < n; p += 16) {
        int rr = p / Ww, cc = p - rr*Ww;
        tlc[p] = xc[rr*50 + cc];
      }
      __syncthreads();
      short* Arow = Apool + (size_t)r*25088 + c*49;
      for (int bb = i; bb < 49; bb += 16) {
        int hb = bb / 7, wb = bb - hb*7;
        int rs = (hb*Hh)/7, re = ((hb+1)*Hh + 6)/7;
        int cs = (wb*Ww)/7, ce = ((wb+1)*Ww + 6)/7;
        float m = -3.402823466e38f;
        for (int rr = rs; rr < re; ++rr)
          for (int cc = cs; cc < ce; ++cc)
            m = fmaxf(m, tlc[rr*Ww + cc]);
        Arow[bb] = f2bf(m);
      }
      __syncthreads();
    }
  }
  gridbar(0);

  // ---- Phase B: gemm1 (Apool[128,25088] @ W1 -> part), one tile per block ----
  gemm_tile(Apool, W1, part, 25088, 3136, 49, b, smem);
  gridbar(1);

  // ---- Phase C: reduce partials + b1 + relu -> fc6 bf16 ----
  {
    const int idx = (b*256 + t) * 4;            // covers 128*4096 floats exactly
    f32x4 sum = {};
#pragma unroll
    for (int s2 = 0; s2 < 8; ++s2)
      sum += *(const f32x4*)(part + (size_t)s2*524288 + idx);
    sum += *(const f32x4*)(b1 + (idx & 4095));
    s16x4 o;
#pragma unroll
    for (int q = 0; q < 4; ++q) o[q] = f2bf(fmaxf(sum[q], 0.f));
    *(s16x4*)(fc6 + idx) = o;
  }
  gridbar(2);

  // ---- Phase D: gemm2 (fc6 @ W2 -> part) ----
  gemm_tile(fc6, W2, part, 4096, 512, 8, b, smem);
  gridbar(3);

  // ---- Phase E: reduce + b2 + relu -> row; row @ {Wloc,Wscore} -> out ----
  if (b < 128) {
    float* row  = (float*)smem;                 // 4096 floats
    float* psum = (float*)(smem + 16384);       // [2][128]
    const int r = b;
    for (int ci = t; ci < 1024; ci += 256) {
      f32x4 sum = {};
#pragma unroll
      for (int s2 = 0; s2 < 8; ++s2)
        sum += *(const f32x4*)(part + (size_t)s2*524288 + r*4096 + ci*4);
      sum += *(const f32x4*)(b2 + ci*4);
      f32x4 o;
#pragma unroll
      for (int q = 0; q < 4; ++q) o[q] = fmaxf(sum[q], 0.f);
      *(f32x4*)(row + ci*4) = o;
    }
    __syncthreads();
    const int c = t & 127, ks = t >> 7;         // ks in {0,1}
    float acc = 0.f;
    if (c < 105) {
      const float* W; int stride, cc;
      if (c < 84) { W = Wloc; stride = 84; cc = c; }
      else        { W = Wscore; stride = 21; cc = c - 84; }
      const int k0 = ks * 2048;
#pragma unroll 4
      for (int k = k0; k < k0 + 2048; ++k)
        acc = fmaf(row[k], W[(size_t)k*stride + cc], acc);
    }
    psum[ks*128 + c] = acc;
    __syncthreads();
    if (ks == 0 && c < 105) {
      float v = psum[c] + psum[128 + c];
      if (c < 84) out[(size_t)r*84 + c] = v + bloc[c];
      else        out[10752 + (size_t)r*21 + (c - 84)] = v + bscore[c - 84];
    }
  }

  // ---- exit handshake: last block restores g_bar to all-zero ----
  __syncthreads();
  if (t == 0) {
    int v = __hip_atomic_fetch_add(&g_bar[4], 1, __ATOMIC_ACQ_REL, __HIP_MEMORY_SCOPE_AGENT);
    if (v == NBLK - 1) {
#pragma unroll
      for (int i = 0; i < 5; ++i)
        __hip_atomic_store(&g_bar[i], 0, __ATOMIC_RELAXED, __HIP_MEMORY_SCOPE_AGENT);
    }
  }
}

// ---------------------------------------------------------------------------
extern "C" void kernel_launch(void* const* d_in, const int* in_sizes, int n_in,
                              void* d_out, int out_size, void* d_ws, size_t ws_size,
                              hipStream_t stream) {
  const float* x      = (const float*)d_in[0];
  const float* rois   = (const float*)d_in[1];
  const float* W1     = (const float*)d_in[2];
  const float* b1     = (const float*)d_in[3];
  const float* W2     = (const float*)d_in[4];
  const float* b2     = (const float*)d_in[5];
  const float* Wloc   = (const float*)d_in[6];
  const float* bloc   = (const float*)d_in[7];
  const float* Wscore = (const float*)d_in[8];
  const float* bscore = (const float*)d_in[9];
  float* out = (float*)d_out;

  char* ws = (char*)d_ws;
  short* Apool = (short*)(ws);              // 128*25088*2 = 6,422,528
  short* fc6   = (short*)(ws + 6422528);    // 128*4096*2  = 1,048,576
  float* part  = (float*)(ws + 9568256);    // 8*128*4096*4 = 16,777,216

  fused_roihead<<<NBLK, 256, 0, stream>>>(x, rois, W1, b1, W2, b2,
                                          Wloc, bloc, Wscore, bscore,
                                          Apool, fc6, part, out);
}

// Round 7
// 621.567 us; speedup vs baseline: 1.2568x; 1.2568x over previous
//
#include <hip/hip_runtime.h>
#include <hip/hip_bf16.h>

// ---------------------------------------------------------------------------
// RoIHead fused persistent kernel, v3: identical to v2 (512 blk x 256 thr,
// 2/CU) except gridbar polls with RELAXED atomic loads + s_sleep backoff and
// a single acquire fence on exit. R5/R6 showed the ACQUIRE-polling barrier
// serialized at ~0.32us/poller/barrier (= invalidate storm): 655us of R6's
// 835us. This round is a clean A/B on the barrier mechanism.
// ---------------------------------------------------------------------------

typedef __attribute__((ext_vector_type(8))) short bf16x8;
typedef __attribute__((ext_vector_type(4))) float f32x4;
typedef __attribute__((ext_vector_type(4))) short s16x4;

typedef const __attribute__((address_space(1))) void gvoid;
typedef __attribute__((address_space(3))) void lvoid;
#define GLD_LDS16(gp, lp) __builtin_amdgcn_global_load_lds((gvoid*)(gp), (lvoid*)(lp), 16, 0, 0)

#define WAITV8() { asm volatile("s_waitcnt vmcnt(8)" ::: "memory"); __builtin_amdgcn_sched_barrier(0); }
#define WAITV0() { asm volatile("s_waitcnt vmcnt(0)" ::: "memory"); __builtin_amdgcn_sched_barrier(0); }
#define BAR() { __builtin_amdgcn_sched_barrier(0); __builtin_amdgcn_s_barrier(); __builtin_amdgcn_sched_barrier(0); }

#define NBLK 512

__device__ int g_bar[8];   // loader-zeroed; exit handshake restores zeros

static __device__ __forceinline__ short f2bf(float f) {   // RNE f32->bf16
  unsigned u = __builtin_bit_cast(unsigned, f);
  u += 0x7fffu + ((u >> 16) & 1u);
  return (short)(u >> 16);
}

static __device__ __forceinline__ void gridbar(int idx) {
  __syncthreads();
  if (threadIdx.x == 0) {
    // RELEASE add: writes back this XCD's L2 (covers all the block's writes)
    __hip_atomic_fetch_add(&g_bar[idx], 1, __ATOMIC_RELEASE, __HIP_MEMORY_SCOPE_AGENT);
    // RELAXED poll: bypasses to LLC, NO invalidates; low probe rate
    while (__hip_atomic_load(&g_bar[idx], __ATOMIC_RELAXED, __HIP_MEMORY_SCOPE_AGENT) < NBLK)
      __builtin_amdgcn_s_sleep(32);
  }
  __syncthreads();
  // single acquire: invalidate stale lines before reading other XCDs' data
  __builtin_amdgcn_fence(__ATOMIC_ACQUIRE, "agent");
}

// ---- one 128x64 output tile of part[s] = A[:,kc0:kc0+KC] @ B[kc0:+KC, n0:+64]
static __device__ void gemm_tile(const short* __restrict__ A, const float* __restrict__ B,
                                 float* __restrict__ part, int K, int KC, int steps,
                                 int tile, char* smem) {
  const int t = threadIdx.x;
  const int w = t >> 6, l = t & 63;
  const int s = tile & 7, nb = tile >> 3;  // s = bid&7: XCD keeps one A-chunk
  const int kc0 = s * KC;

  char* const bA[2] = { smem,         smem + 16384 };
  char* const bB[2] = { smem + 32768, smem + 49152 };

  int aoff[4], boff[4];
#pragma unroll
  for (int p = 0; p < 4; ++p) {
    int o = (p*256 + t) * 16;                 // linear LDS byte offset [0,16384)
    int oa = o ^ (((o >> 7) & 7) << 4);       // inverse A swizzle (involution)
    aoff[p] = (oa >> 7) * (K*2) + (oa & 127);
    int ob = o ^ (((o >> 11) & 1) << 6);      // inverse B swizzle (involution)
    boff[p] = (ob >> 8) * 16384 + (ob & 255);
  }
  const int r15 = l & 15, kh = l >> 4;
  const int xa = (r15 & 7) << 4;
  const int aoj0 = r15*128 + ((kh*16) ^ xa);
  const int aoj1 = r15*128 + ((64 + kh*16) ^ xa);
  const int bo0  = (kh*8*256 + (w*16 + r15)*4) ^ ((kh & 1) << 6);

  const char* Ak = (const char*)A + kc0*2;
  const char* Bk = (const char*)B + (size_t)kc0*16384 + (size_t)(nb*64)*4;

  f32x4 acc[8] = {};
  int cur = 0;
#pragma unroll
  for (int p = 0; p < 4; ++p) {
    GLD_LDS16(Ak + aoff[p], bA[0] + (p*256 + w*64)*16);
    GLD_LDS16(Bk + boff[p], bB[0] + (p*256 + w*64)*16);
  }
  Ak += 128; Bk += (size_t)64*16384;

  for (int st = 0; st < steps; ++st) {
    if (st + 1 < steps) {
      char* dA = bA[cur^1]; char* dB = bB[cur^1];
#pragma unroll
      for (int p = 0; p < 4; ++p) {
        GLD_LDS16(Ak + aoff[p], dA + (p*256 + w*64)*16);
        GLD_LDS16(Bk + boff[p], dB + (p*256 + w*64)*16);
      }
      Ak += 128; Bk += (size_t)64*16384;
      WAITV8();                    // my tile-st loads landed; next 8 in flight
    } else {
      WAITV0();
    }
    BAR();
    const char* lAb = bA[cur]; const char* lBb = bB[cur];
#pragma unroll
    for (int j = 0; j < 2; ++j) {
      const int ao = j ? aoj1 : aoj0;
      const int bo = j*8192 + bo0;
      float bf[8];
#pragma unroll
      for (int i2 = 0; i2 < 8; ++i2) bf[i2] = *(const float*)(lBb + bo + i2*256);
      bf16x8 bfrag;
#pragma unroll
      for (int i2 = 0; i2 < 8; ++i2) bfrag[i2] = f2bf(bf[i2]);
#pragma unroll
      for (int mf = 0; mf < 8; ++mf) {
        bf16x8 afrag = *(const bf16x8*)(lAb + mf*2048 + ao);
        acc[mf] = __builtin_amdgcn_mfma_f32_16x16x32_bf16(afrag, bfrag, acc[mf], 0, 0, 0);
      }
    }
    BAR();
    cur ^= 1;
  }
  // C/D: col = lane&15, row = (lane>>4)*4 + q
  const int n = nb*64 + w*16 + r15;
  float* prow = part + (size_t)s*524288 + n;
#pragma unroll
  for (int mf = 0; mf < 8; ++mf) {
    int m0 = mf*16 + kh*4;
#pragma unroll
    for (int q = 0; q < 4; ++q)
      prow[(m0 + q)*4096] = acc[mf][q];
  }
}

extern "C" __global__ void __launch_bounds__(256)
fused_roihead(const float* __restrict__ x, const float* __restrict__ rois,
              const float* __restrict__ W1, const float* __restrict__ b1,
              const float* __restrict__ W2, const float* __restrict__ b2,
              const float* __restrict__ Wloc, const float* __restrict__ bloc,
              const float* __restrict__ Wscore, const float* __restrict__ bscore,
              short* __restrict__ Apool, short* __restrict__ fc6,
              float* __restrict__ part, float* __restrict__ out) {
  __shared__ char smem[65536];
  const int t = threadIdx.x, b = blockIdx.x;

  // ---- Phase A: ROI pool -> Apool bf16 [128][25088]; 4096 units, 8/block ----
  {
    float* tl = (float*)smem;                   // [16][292] floats
    const int cl = t >> 4, i = t & 15;
    float* tlc = tl + cl*292;
    for (int u = 0; u < 8; ++u) {
      const int unit = u*NBLK + b;              // [0,4096)
      const int r = unit >> 5, cg = unit & 31;
      const int c = cg*16 + cl;
      const float y1 = rois[r*4+0], x1 = rois[r*4+1], y2 = rois[r*4+2], x2 = rois[r*4+3];
      const int h0 = (int)(y1*0.0625f), h1 = (int)(y2*0.0625f) + 1;
      const int w0 = (int)(x1*0.0625f), w1 = (int)(x2*0.0625f) + 1;
      const int Hh = h1-h0, Ww = w1-w0, n = Hh*Ww;   // <=17 each
      const float* xc = x + c*1850 + h0*50 + w0;
      for (int p = i; p < n; p += 16) {
        int rr = p / Ww, cc = p - rr*Ww;
        tlc[p] = xc[rr*50 + cc];
      }
      __syncthreads();
      short* Arow = Apool + (size_t)r*25088 + c*49;
      for (int bb = i; bb < 49; bb += 16) {
        int hb = bb / 7, wb = bb - hb*7;
        int rs = (hb*Hh)/7, re = ((hb+1)*Hh + 6)/7;
        int cs = (wb*Ww)/7, ce = ((wb+1)*Ww + 6)/7;
        float m = -3.402823466e38f;
        for (int rr = rs; rr < re; ++rr)
          for (int cc = cs; cc < ce; ++cc)
            m = fmaxf(m, tlc[rr*Ww + cc]);
        Arow[bb] = f2bf(m);
      }
      __syncthreads();
    }
  }
  gridbar(0);

  // ---- Phase B: gemm1 (Apool[128,25088] @ W1 -> part), one tile per block ----
  gemm_tile(Apool, W1, part, 25088, 3136, 49, b, smem);
  gridbar(1);

  // ---- Phase C: reduce partials + b1 + relu -> fc6 bf16 ----
  {
    const int idx = (b*256 + t) * 4;            // covers 128*4096 floats exactly
    f32x4 sum = {};
#pragma unroll
    for (int s2 = 0; s2 < 8; ++s2)
      sum += *(const f32x4*)(part + (size_t)s2*524288 + idx);
    sum += *(const f32x4*)(b1 + (idx & 4095));
    s16x4 o;
#pragma unroll
    for (int q = 0; q < 4; ++q) o[q] = f2bf(fmaxf(sum[q], 0.f));
    *(s16x4*)(fc6 + idx) = o;
  }
  gridbar(2);

  // ---- Phase D: gemm2 (fc6 @ W2 -> part) ----
  gemm_tile(fc6, W2, part, 4096, 512, 8, b, smem);
  gridbar(3);

  // ---- Phase E: reduce + b2 + relu -> row; row @ {Wloc,Wscore} -> out ----
  if (b < 128) {
    float* row  = (float*)smem;                 // 4096 floats
    float* psum = (float*)(smem + 16384);       // [2][128]
    const int r = b;
    for (int ci = t; ci < 1024; ci += 256) {
      f32x4 sum = {};
#pragma unroll
      for (int s2 = 0; s2 < 8; ++s2)
        sum += *(const f32x4*)(part + (size_t)s2*524288 + r*4096 + ci*4);
      sum += *(const f32x4*)(b2 + ci*4);
      f32x4 o;
#pragma unroll
      for (int q = 0; q < 4; ++q) o[q] = fmaxf(sum[q], 0.f);
      *(f32x4*)(row + ci*4) = o;
    }
    __syncthreads();
    const int c = t & 127, ks = t >> 7;         // ks in {0,1}
    float acc = 0.f;
    if (c < 105) {
      const float* W; int stride, cc;
      if (c < 84) { W = Wloc; stride = 84; cc = c; }
      else        { W = Wscore; stride = 21; cc = c - 84; }
      const int k0 = ks * 2048;
#pragma unroll 4
      for (int k = k0; k < k0 + 2048; ++k)
        acc = fmaf(row[k], W[(size_t)k*stride + cc], acc);
    }
    psum[ks*128 + c] = acc;
    __syncthreads();
    if (ks == 0 && c < 105) {
      float v = psum[c] + psum[128 + c];
      if (c < 84) out[(size_t)r*84 + c] = v + bloc[c];
      else        out[10752 + (size_t)r*21 + (c - 84)] = v + bscore[c - 84];
    }
  }

  // ---- exit handshake: last block restores g_bar to all-zero ----
  __syncthreads();
  if (t == 0) {
    int v = __hip_atomic_fetch_add(&g_bar[4], 1, __ATOMIC_ACQ_REL, __HIP_MEMORY_SCOPE_AGENT);
    if (v == NBLK - 1) {
#pragma unroll
      for (int i = 0; i < 5; ++i)
        __hip_atomic_store(&g_bar[i], 0, __ATOMIC_RELAXED, __HIP_MEMORY_SCOPE_AGENT);
    }
  }
}

// ---------------------------------------------------------------------------
extern "C" void kernel_launch(void* const* d_in, const int* in_sizes, int n_in,
                              void* d_out, int out_size, void* d_ws, size_t ws_size,
                              hipStream_t stream) {
  const float* x      = (const float*)d_in[0];
  const float* rois   = (const float*)d_in[1];
  const float* W1     = (const float*)d_in[2];
  const float* b1     = (const float*)d_in[3];
  const float* W2     = (const float*)d_in[4];
  const float* b2     = (const float*)d_in[5];
  const float* Wloc   = (const float*)d_in[6];
  const float* bloc   = (const float*)d_in[7];
  const float* Wscore = (const float*)d_in[8];
  const float* bscore = (const float*)d_in[9];
  float* out = (float*)d_out;

  char* ws = (char*)d_ws;
  short* Apool = (short*)(ws);              // 128*25088*2 = 6,422,528
  short* fc6   = (short*)(ws + 6422528);    // 128*4096*2  = 1,048,576
  float* part  = (float*)(ws + 9568256);    // 8*128*4096*4 = 16,777,216

  fused_roihead<<<NBLK, 256, 0, stream>>>(x, rois, W1, b1, W2, b2,
                                          Wloc, bloc, Wscore, bscore,
                                          Apool, fc6, part, out);
}

// Round 8
// 533.260 us; speedup vs baseline: 1.4650x; 1.1656x over previous
//
#include <hip/hip_runtime.h>
#include <hip/hip_bf16.h>

// ---------------------------------------------------------------------------
// RoIHead fused persistent kernel, v4: identical to v3 except the grid barrier
// uses per-block padded arrival SLOTS (store-release, no RMW) + a collector
// block that sweeps slots and sets per-group release flags. R5/R6/R7 data
// isolated the cost to serialized same-line agent-scope RMWs (~250ns each);
// this barrier has zero shared-line RMWs.
// ---------------------------------------------------------------------------

typedef __attribute__((ext_vector_type(8))) short bf16x8;
typedef __attribute__((ext_vector_type(4))) float f32x4;
typedef __attribute__((ext_vector_type(4))) short s16x4;

typedef const __attribute__((address_space(1))) void gvoid;
typedef __attribute__((address_space(3))) void lvoid;
#define GLD_LDS16(gp, lp) __builtin_amdgcn_global_load_lds((gvoid*)(gp), (lvoid*)(lp), 16, 0, 0)

#define WAITV8() { asm volatile("s_waitcnt vmcnt(8)" ::: "memory"); __builtin_amdgcn_sched_barrier(0); }
#define WAITV0() { asm volatile("s_waitcnt vmcnt(0)" ::: "memory"); __builtin_amdgcn_sched_barrier(0); }
#define BAR() { __builtin_amdgcn_sched_barrier(0); __builtin_amdgcn_s_barrier(); __builtin_amdgcn_sched_barrier(0); }

#define NBLK 512

__device__ int g_slots[NBLK * 16];   // 64B-padded per-block arrival slots (loader-zeroed)
__device__ int g_flags[4 * 8 * 16];  // [barrier][group] 64B-padded release flags

static __device__ __forceinline__ short f2bf(float f) {   // RNE f32->bf16
  unsigned u = __builtin_bit_cast(unsigned, f);
  u += 0x7fffu + ((u >> 16) & 1u);
  return (short)(u >> 16);
}

// store/collector grid barrier: no shared-line RMWs.
static __device__ __forceinline__ void gridbar(int idx, int b) {
  __syncthreads();
  const int t = threadIdx.x;
  if (t == 0)
    __hip_atomic_store(&g_slots[b * 16], idx + 1, __ATOMIC_RELEASE, __HIP_MEMORY_SCOPE_AGENT);
  if (b == 0 && t < 64) {
    for (;;) {
      bool mine = true;
      for (int i = t; i < NBLK; i += 64)
        mine = mine && (__hip_atomic_load(&g_slots[i * 16], __ATOMIC_RELAXED,
                                          __HIP_MEMORY_SCOPE_AGENT) >= idx + 1);
      if (__all(mine)) break;
      __builtin_amdgcn_s_sleep(8);
    }
    __builtin_amdgcn_fence(__ATOMIC_ACQUIRE, "agent");   // chain arrivals -> flags
    if (t < 8)
      __hip_atomic_store(&g_flags[(idx * 8 + t) * 16], 1, __ATOMIC_RELEASE,
                         __HIP_MEMORY_SCOPE_AGENT);
  }
  if (t == 0) {
    while (__hip_atomic_load(&g_flags[(idx * 8 + (b & 7)) * 16], __ATOMIC_RELAXED,
                             __HIP_MEMORY_SCOPE_AGENT) == 0)
      __builtin_amdgcn_s_sleep(16);
  }
  __syncthreads();
  __builtin_amdgcn_fence(__ATOMIC_ACQUIRE, "agent");
}

// ---- one 128x64 output tile of part[s] = A[:,kc0:kc0+KC] @ B[kc0:+KC, n0:+64]
static __device__ void gemm_tile(const short* __restrict__ A, const float* __restrict__ B,
                                 float* __restrict__ part, int K, int KC, int steps,
                                 int tile, char* smem) {
  const int t = threadIdx.x;
  const int w = t >> 6, l = t & 63;
  const int s = tile & 7, nb = tile >> 3;  // s = bid&7: XCD keeps one A-chunk
  const int kc0 = s * KC;

  char* const bA[2] = { smem,         smem + 16384 };
  char* const bB[2] = { smem + 32768, smem + 49152 };

  int aoff[4], boff[4];
#pragma unroll
  for (int p = 0; p < 4; ++p) {
    int o = (p*256 + t) * 16;                 // linear LDS byte offset [0,16384)
    int oa = o ^ (((o >> 7) & 7) << 4);       // inverse A swizzle (involution)
    aoff[p] = (oa >> 7) * (K*2) + (oa & 127);
    int ob = o ^ (((o >> 11) & 1) << 6);      // inverse B swizzle (involution)
    boff[p] = (ob >> 8) * 16384 + (ob & 255);
  }
  const int r15 = l & 15, kh = l >> 4;
  const int xa = (r15 & 7) << 4;
  const int aoj0 = r15*128 + ((kh*16) ^ xa);
  const int aoj1 = r15*128 + ((64 + kh*16) ^ xa);
  const int bo0  = (kh*8*256 + (w*16 + r15)*4) ^ ((kh & 1) << 6);

  const char* Ak = (const char*)A + kc0*2;
  const char* Bk = (const char*)B + (size_t)kc0*16384 + (size_t)(nb*64)*4;

  f32x4 acc[8] = {};
  int cur = 0;
#pragma unroll
  for (int p = 0; p < 4; ++p) {
    GLD_LDS16(Ak + aoff[p], bA[0] + (p*256 + w*64)*16);
    GLD_LDS16(Bk + boff[p], bB[0] + (p*256 + w*64)*16);
  }
  Ak += 128; Bk += (size_t)64*16384;

  for (int st = 0; st < steps; ++st) {
    if (st + 1 < steps) {
      char* dA = bA[cur^1]; char* dB = bB[cur^1];
#pragma unroll
      for (int p = 0; p < 4; ++p) {
        GLD_LDS16(Ak + aoff[p], dA + (p*256 + w*64)*16);
        GLD_LDS16(Bk + boff[p], dB + (p*256 + w*64)*16);
      }
      Ak += 128; Bk += (size_t)64*16384;
      WAITV8();                    // my tile-st loads landed; next 8 in flight
    } else {
      WAITV0();
    }
    BAR();
    const char* lAb = bA[cur]; const char* lBb = bB[cur];
#pragma unroll
    for (int j = 0; j < 2; ++j) {
      const int ao = j ? aoj1 : aoj0;
      const int bo = j*8192 + bo0;
      float bf[8];
#pragma unroll
      for (int i2 = 0; i2 < 8; ++i2) bf[i2] = *(const float*)(lBb + bo + i2*256);
      bf16x8 bfrag;
#pragma unroll
      for (int i2 = 0; i2 < 8; ++i2) bfrag[i2] = f2bf(bf[i2]);
#pragma unroll
      for (int mf = 0; mf < 8; ++mf) {
        bf16x8 afrag = *(const bf16x8*)(lAb + mf*2048 + ao);
        acc[mf] = __builtin_amdgcn_mfma_f32_16x16x32_bf16(afrag, bfrag, acc[mf], 0, 0, 0);
      }
    }
    BAR();
    cur ^= 1;
  }
  // C/D: col = lane&15, row = (lane>>4)*4 + q
  const int n = nb*64 + w*16 + r15;
  float* prow = part + (size_t)s*524288 + n;
#pragma unroll
  for (int mf = 0; mf < 8; ++mf) {
    int m0 = mf*16 + kh*4;
#pragma unroll
    for (int q = 0; q < 4; ++q)
      prow[(m0 + q)*4096] = acc[mf][q];
  }
}

extern "C" __global__ void __launch_bounds__(256)
fused_roihead(const float* __restrict__ x, const float* __restrict__ rois,
              const float* __restrict__ W1, const float* __restrict__ b1,
              const float* __restrict__ W2, const float* __restrict__ b2,
              const float* __restrict__ Wloc, const float* __restrict__ bloc,
              const float* __restrict__ Wscore, const float* __restrict__ bscore,
              short* __restrict__ Apool, short* __restrict__ fc6,
              float* __restrict__ part, float* __restrict__ out) {
  __shared__ char smem[65536];
  const int t = threadIdx.x, b = blockIdx.x;

  // ---- Phase A: ROI pool -> Apool bf16 [128][25088]; 4096 units, 8/block ----
  {
    float* tl = (float*)smem;                   // [16][292] floats
    const int cl = t >> 4, i = t & 15;
    float* tlc = tl + cl*292;
    for (int u = 0; u < 8; ++u) {
      const int unit = u*NBLK + b;              // [0,4096)
      const int r = unit >> 5, cg = unit & 31;
      const int c = cg*16 + cl;
      const float y1 = rois[r*4+0], x1 = rois[r*4+1], y2 = rois[r*4+2], x2 = rois[r*4+3];
      const int h0 = (int)(y1*0.0625f), h1 = (int)(y2*0.0625f) + 1;
      const int w0 = (int)(x1*0.0625f), w1 = (int)(x2*0.0625f) + 1;
      const int Hh = h1-h0, Ww = w1-w0, n = Hh*Ww;   // <=17 each
      const float* xc = x + c*1850 + h0*50 + w0;
      for (int p = i; p < n; p += 16) {
        int rr = p / Ww, cc = p - rr*Ww;
        tlc[p] = xc[rr*50 + cc];
      }
      __syncthreads();
      short* Arow = Apool + (size_t)r*25088 + c*49;
      for (int bb = i; bb < 49; bb += 16) {
        int hb = bb / 7, wb = bb - hb*7;
        int rs = (hb*Hh)/7, re = ((hb+1)*Hh + 6)/7;
        int cs = (wb*Ww)/7, ce = ((wb+1)*Ww + 6)/7;
        float m = -3.402823466e38f;
        for (int rr = rs; rr < re; ++rr)
          for (int cc = cs; cc < ce; ++cc)
            m = fmaxf(m, tlc[rr*Ww + cc]);
        Arow[bb] = f2bf(m);
      }
      __syncthreads();
    }
  }
  gridbar(0, b);

  // ---- Phase B: gemm1 (Apool[128,25088] @ W1 -> part), one tile per block ----
  gemm_tile(Apool, W1, part, 25088, 3136, 49, b, smem);
  gridbar(1, b);

  // ---- Phase C: reduce partials + b1 + relu -> fc6 bf16 ----
  {
    const int idx = (b*256 + t) * 4;            // covers 128*4096 floats exactly
    f32x4 sum = {};
#pragma unroll
    for (int s2 = 0; s2 < 8; ++s2)
      sum += *(const f32x4*)(part + (size_t)s2*524288 + idx);
    sum += *(const f32x4*)(b1 + (idx & 4095));
    s16x4 o;
#pragma unroll
    for (int q = 0; q < 4; ++q) o[q] = f2bf(fmaxf(sum[q], 0.f));
    *(s16x4*)(fc6 + idx) = o;
  }
  gridbar(2, b);

  // ---- Phase D: gemm2 (fc6 @ W2 -> part) ----
  gemm_tile(fc6, W2, part, 4096, 512, 8, b, smem);
  gridbar(3, b);

  // ---- Phase E: reduce + b2 + relu -> row; row @ {Wloc,Wscore} -> out ----
  if (b < 128) {
    float* row  = (float*)smem;                 // 4096 floats
    float* psum = (float*)(smem + 16384);       // [2][128]
    const int r = b;
    for (int ci = t; ci < 1024; ci += 256) {
      f32x4 sum = {};
#pragma unroll
      for (int s2 = 0; s2 < 8; ++s2)
        sum += *(const f32x4*)(part + (size_t)s2*524288 + r*4096 + ci*4);
      sum += *(const f32x4*)(b2 + ci*4);
      f32x4 o;
#pragma unroll
      for (int q = 0; q < 4; ++q) o[q] = fmaxf(sum[q], 0.f);
      *(f32x4*)(row + ci*4) = o;
    }
    __syncthreads();
    const int c = t & 127, ks = t >> 7;         // ks in {0,1}
    float acc = 0.f;
    if (c < 105) {
      const float* W; int stride, cc;
      if (c < 84) { W = Wloc; stride = 84; cc = c; }
      else        { W = Wscore; stride = 21; cc = c - 84; }
      const int k0 = ks * 2048;
#pragma unroll 4
      for (int k = k0; k < k0 + 2048; ++k)
        acc = fmaf(row[k], W[(size_t)k*stride + cc], acc);
    }
    psum[ks*128 + c] = acc;
    __syncthreads();
    if (ks == 0 && c < 105) {
      float v = psum[c] + psum[128 + c];
      if (c < 84) out[(size_t)r*84 + c] = v + bloc[c];
      else        out[10752 + (size_t)r*21 + (c - 84)] = v + bscore[c - 84];
    }
  }

  // ---- exit barrier (idx 4): collector restores slots/flags to zero ----
  __syncthreads();
  if (t == 0)
    __hip_atomic_store(&g_slots[b * 16], 5, __ATOMIC_RELEASE, __HIP_MEMORY_SCOPE_AGENT);
  if (b == 0 && t < 64) {
    for (;;) {
      bool mine = true;
      for (int i = t; i < NBLK; i += 64)
        mine = mine && (__hip_atomic_load(&g_slots[i * 16], __ATOMIC_RELAXED,
                                          __HIP_MEMORY_SCOPE_AGENT) >= 5);
      if (__all(mine)) break;
      __builtin_amdgcn_s_sleep(8);
    }
    for (int i = t; i < NBLK; i += 64)
      __hip_atomic_store(&g_slots[i * 16], 0, __ATOMIC_RELAXED, __HIP_MEMORY_SCOPE_AGENT);
    if (t < 32)
      __hip_atomic_store(&g_flags[t * 16], 0, __ATOMIC_RELAXED, __HIP_MEMORY_SCOPE_AGENT);
  }
}

// ---------------------------------------------------------------------------
extern "C" void kernel_launch(void* const* d_in, const int* in_sizes, int n_in,
                              void* d_out, int out_size, void* d_ws, size_t ws_size,
                              hipStream_t stream) {
  const float* x      = (const float*)d_in[0];
  const float* rois   = (const float*)d_in[1];
  const float* W1     = (const float*)d_in[2];
  const float* b1     = (const float*)d_in[3];
  const float* W2     = (const float*)d_in[4];
  const float* b2     = (const float*)d_in[5];
  const float* Wloc   = (const float*)d_in[6];
  const float* bloc   = (const float*)d_in[7];
  const float* Wscore = (const float*)d_in[8];
  const float* bscore = (const float*)d_in[9];
  float* out = (float*)d_out;

  char* ws = (char*)d_ws;
  short* Apool = (short*)(ws);              // 128*25088*2 = 6,422,528
  short* fc6   = (short*)(ws + 6422528);    // 128*4096*2  = 1,048,576
  float* part  = (float*)(ws + 9568256);    // 8*128*4096*4 = 16,777,216

  fused_roihead<<<NBLK, 256, 0, stream>>>(x, rois, W1, b1, W2, b2,
                                          Wloc, bloc, Wscore, bscore,
                                          Apool, fc6, part, out);
}

// Round 9
// 277.304 us; speedup vs baseline: 2.8172x; 1.9230x over previous
//
#include <hip/hip_runtime.h>
#include <hip/hip_bf16.h>

// ---------------------------------------------------------------------------
// RoIHead 4-kernel pipeline (back to proven R2 structure, minus 2 launches):
//  K1 roipool (+ zero completion counters)
//  K2 gemm1 split-K=8  + TAIL: last block per column-group reduces partials
//     + b1 + relu -> fc6 (bf16)          [kills reduce0 kernel]
//  K3 gemm2 split-K=8 (unchanged)
//  K4 reduce1 + final fused              [kills reduce1 kernel + fc7 buffer]
// R5-R8 showed grid-barrier fusion costs ~80-100us/barrier on this chip; the
// tail-fusion here uses 64 padded low-contention counters instead.
// ---------------------------------------------------------------------------

typedef __attribute__((ext_vector_type(8))) short bf16x8;
typedef __attribute__((ext_vector_type(4))) float f32x4;
typedef __attribute__((ext_vector_type(4))) short s16x4;

typedef const __attribute__((address_space(1))) void gvoid;
typedef __attribute__((address_space(3))) void lvoid;
#define GLD_LDS16(gp, lp) __builtin_amdgcn_global_load_lds((gvoid*)(gp), (lvoid*)(lp), 16, 0, 0)

#define WAITV8() { asm volatile("s_waitcnt vmcnt(8)" ::: "memory"); __builtin_amdgcn_sched_barrier(0); }
#define WAITV0() { asm volatile("s_waitcnt vmcnt(0)" ::: "memory"); __builtin_amdgcn_sched_barrier(0); }
#define BAR() { __builtin_amdgcn_sched_barrier(0); __builtin_amdgcn_s_barrier(); __builtin_amdgcn_sched_barrier(0); }

static __device__ __forceinline__ short f2bf(float f) {   // RNE f32->bf16
  unsigned u = __builtin_bit_cast(unsigned, f);
  u += 0x7fffu + ((u >> 16) & 1u);
  return (short)(u >> 16);
}

// ---------------- K1: ROI pool -> A bf16 [128][25088]; zero counters --------
__global__ __launch_bounds__(256) void roipool_kernel(
    const float* __restrict__ x, const float* __restrict__ rois,
    __hip_bfloat16* __restrict__ A, int* __restrict__ cnt) {
  if (blockIdx.x == 0 && blockIdx.y == 0 && threadIdx.x < 64)
    cnt[threadIdx.x * 16] = 0;                 // re-zero every replay
  const int cg = blockIdx.x;      // 0..31, 16 channels each
  const int r  = blockIdx.y;      // 0..127
  const float y1 = rois[r*4+0], x1 = rois[r*4+1], y2 = rois[r*4+2], x2 = rois[r*4+3];
  const int h0 = (int)(y1 * 0.0625f);
  const int h1 = (int)(y2 * 0.0625f) + 1;
  const int w0 = (int)(x1 * 0.0625f);
  const int w1 = (int)(x2 * 0.0625f) + 1;
  const int Hh = h1 - h0, Ww = w1 - w0;        // <= 17 each
  const int n = Hh * Ww;                       // <= 289
  __shared__ float tile[16][292];
  const int cl = threadIdx.x >> 4, i = threadIdx.x & 15;
  const int c = cg*16 + cl;
  const float* xc = x + c*1850 + h0*50 + w0;   // x: [512][37][50]
  for (int p = i; p < n; p += 16) {
    int rr = p / Ww, cc = p - rr*Ww;
    tile[cl][p] = xc[rr*50 + cc];
  }
  __syncthreads();
  __hip_bfloat16* Arow = A + (size_t)r*25088 + c*49;
  for (int b = i; b < 49; b += 16) {
    int hb = b / 7, wb = b - hb*7;
    int rs = (hb*Hh)/7,  re = ((hb+1)*Hh + 6)/7;
    int cs = (wb*Ww)/7,  ce = ((wb+1)*Ww + 6)/7;
    float m = -3.402823466e38f;
    for (int rr2 = rs; rr2 < re; ++rr2)
      for (int cc2 = cs; cc2 < ce; ++cc2)
        m = fmaxf(m, tile[cl][rr2*Ww + cc2]);
    Arow[b] = __float2bfloat16(m);
  }
}

// ---------------- K2/K3: MFMA split-K GEMM (R2 body) + optional reduce tail -
template <int TAIL>
__global__ __launch_bounds__(256) void gemm_kernel(
    const __hip_bfloat16* __restrict__ A,  // [128][K] bf16
    const float* __restrict__ B,           // [K][4096] f32
    float* __restrict__ part,              // [8][128][4096] f32
    int K, int KC,
    const float* __restrict__ bias,        // b1 (TAIL only)
    short* __restrict__ fcout,             // fc6 (TAIL only)
    int* __restrict__ cnt) {               // 64 padded counters (TAIL only)
  __shared__ short lA[2][8192];    // 2 x 16 KB
  __shared__ float lB[2][4096];    // 2 x 16 KB
  __shared__ int s_old;
  const int t = threadIdx.x;
  const int w = t >> 6, l = t & 63;
  const int bid = blockIdx.x;
  const int s  = bid & 7;          // XCD-locality: same s stays on one XCD
  const int nb = bid >> 3;
  const int kc0 = s * KC;
  const int Arow_bytes = K * 2;

  int aoff[4], boff[4];
#pragma unroll
  for (int p = 0; p < 4; ++p) {
    int o = (p*256 + t) * 16;                     // linear LDS byte offset
    int oa = o ^ (((o >> 7) & 7) << 4);           // inverse A swizzle (involution)
    aoff[p] = (oa >> 7) * Arow_bytes + (oa & 127);
    int ob = o ^ (((o >> 11) & 1) << 6);          // inverse B swizzle (involution)
    boff[p] = (ob >> 8) * 16384 + (ob & 255);
  }
  const int r15 = l & 15, kh = l >> 4;
  const int xa = (r15 & 7) << 4;
  const int aoj0 = r15*128 + ((kh*16) ^ xa);
  const int aoj1 = r15*128 + (((64) + kh*16) ^ xa);
  const int bo0  = ((kh*8)*256 + (w*16 + r15)*4) ^ ((kh & 1) << 6);

  const char* Ak = (const char*)A + kc0*2;
  const char* Bk = (const char*)B + (size_t)kc0*16384 + nb*256;

  f32x4 acc[8] = {};
  const int steps = KC >> 6;
  int cur = 0;

#pragma unroll
  for (int p = 0; p < 4; ++p) {
    GLD_LDS16(Ak + aoff[p], (char*)lA[0] + (p*256 + w*64)*16);
    GLD_LDS16(Bk + boff[p], (char*)lB[0] + (p*256 + w*64)*16);
  }
  Ak += 128; Bk += 64 * 16384;

  for (int st = 0; st < steps; ++st) {
    if (st + 1 < steps) {
      char* dA = (char*)lA[cur ^ 1];
      char* dB = (char*)lB[cur ^ 1];
#pragma unroll
      for (int p = 0; p < 4; ++p) {
        GLD_LDS16(Ak + aoff[p], dA + (p*256 + w*64)*16);
        GLD_LDS16(Bk + boff[p], dB + (p*256 + w*64)*16);
      }
      Ak += 128; Bk += 64 * 16384;
      WAITV8();
    } else {
      WAITV0();
    }
    BAR();
    const char* lAb = (const char*)lA[cur];
    const char* lBb = (const char*)lB[cur];
#pragma unroll
    for (int j = 0; j < 2; ++j) {
      const int ao = j ? aoj1 : aoj0;
      const int bo = (j ? 8192 : 0) + bo0;
      float bf[8];
#pragma unroll
      for (int i2 = 0; i2 < 8; ++i2)
        bf[i2] = *(const float*)(lBb + bo + i2*256);
      bf16x8 bfrag;
#pragma unroll
      for (int i2 = 0; i2 < 8; ++i2) bfrag[i2] = f2bf(bf[i2]);
#pragma unroll
      for (int mf = 0; mf < 8; ++mf) {
        bf16x8 afrag = *(const bf16x8*)(lAb + mf*2048 + ao);
        acc[mf] = __builtin_amdgcn_mfma_f32_16x16x32_bf16(afrag, bfrag, acc[mf], 0, 0, 0);
      }
    }
    BAR();
    cur ^= 1;
  }
  // C/D: col = lane&15, row = (lane>>4)*4 + q
  const int n = nb*64 + w*16 + r15;
  float* prow = part + (size_t)s*524288 + n;
#pragma unroll
  for (int mf = 0; mf < 8; ++mf) {
    int m0 = mf*16 + kh*4;
#pragma unroll
    for (int q = 0; q < 4; ++q)
      prow[(m0 + q)*4096] = acc[mf][q];
  }

  if (TAIL) {
    // completion counter for this column-group; 8th arriver reduces.
    // ACQ_REL RMW: release flushes this block's part-writes (L2 wb);
    // acquire orders after the 7 prior releases in the same mod-order.
    if (t == 0)
      s_old = __hip_atomic_fetch_add(&cnt[nb * 16], 1, __ATOMIC_ACQ_REL,
                                     __HIP_MEMORY_SCOPE_AGENT);
    __syncthreads();
    if (s_old == 7) {
      __builtin_amdgcn_fence(__ATOMIC_ACQUIRE, "agent");
      // reduce cols [nb*64, nb*64+64) over 8 partials + bias + relu -> fcout
#pragma unroll
      for (int it = 0; it < 8; ++it) {
        const int e = it*256 + t;            // 0..2047
        const int m = e >> 4;                // row 0..127
        const int col = nb*64 + (e & 15)*4;  // col group
        f32x4 sum = {};
#pragma unroll
        for (int s2 = 0; s2 < 8; ++s2)
          sum += *(const f32x4*)(part + (size_t)s2*524288 + m*4096 + col);
        sum += *(const f32x4*)(bias + col);
        s16x4 o;
#pragma unroll
        for (int q = 0; q < 4; ++q) o[q] = f2bf(fmaxf(sum[q], 0.f));
        *(s16x4*)(fcout + (size_t)m*4096 + col) = o;
      }
    }
  }
}

// ---------------- K4: reduce partials + b2 + relu -> row; row @ {Wloc,Wscore}
__global__ __launch_bounds__(512) void final_kernel(
    const float* __restrict__ part, const float* __restrict__ b2,
    const float* __restrict__ Wloc, const float* __restrict__ bloc,
    const float* __restrict__ Wscore, const float* __restrict__ bscore,
    float* __restrict__ out) {
  __shared__ float row[4096];
  __shared__ float psum[4][128];
  const int r = blockIdx.x, t = threadIdx.x;
  for (int ci = t; ci < 1024; ci += 512) {
    f32x4 sum = {};
#pragma unroll
    for (int s2 = 0; s2 < 8; ++s2)
      sum += *(const f32x4*)(part + (size_t)s2*524288 + r*4096 + ci*4);
    sum += *(const f32x4*)(b2 + ci*4);
    f32x4 o;
#pragma unroll
    for (int q = 0; q < 4; ++q) o[q] = fmaxf(sum[q], 0.f);
    *(f32x4*)&row[ci*4] = o;
  }
  __syncthreads();
  const int c = t & 127, ks = t >> 7;
  float acc = 0.f;
  if (c < 105) {
    const float* W; int stride, cc;
    if (c < 84) { W = Wloc; stride = 84; cc = c; }
    else        { W = Wscore; stride = 21; cc = c - 84; }
    const int k0 = ks * 1024;
#pragma unroll 4
    for (int k = k0; k < k0 + 1024; ++k)
      acc = fmaf(row[k], W[(size_t)k*stride + cc], acc);
  }
  psum[ks][c] = acc;
  __syncthreads();
  if (ks == 0 && c < 105) {
    float v = psum[0][c] + psum[1][c] + psum[2][c] + psum[3][c];
    if (c < 84) out[(size_t)r*84 + c] = v + bloc[c];
    else        out[10752 + (size_t)r*21 + (c - 84)] = v + bscore[c - 84];
  }
}

// ---------------------------------------------------------------------------
extern "C" void kernel_launch(void* const* d_in, const int* in_sizes, int n_in,
                              void* d_out, int out_size, void* d_ws, size_t ws_size,
                              hipStream_t stream) {
  const float* x      = (const float*)d_in[0];
  const float* rois   = (const float*)d_in[1];
  const float* W1     = (const float*)d_in[2];
  const float* b1     = (const float*)d_in[3];
  const float* W2     = (const float*)d_in[4];
  const float* b2     = (const float*)d_in[5];
  const float* Wloc   = (const float*)d_in[6];
  const float* bloc   = (const float*)d_in[7];
  const float* Wscore = (const float*)d_in[8];
  const float* bscore = (const float*)d_in[9];
  float* out = (float*)d_out;

  char* ws = (char*)d_ws;
  __hip_bfloat16* Apool = (__hip_bfloat16*)(ws);            // 128*25088*2 = 6,422,528
  short*          fc6   = (short*)(ws + 6422528);           // 128*4096*2  = 1,048,576
  float*          part  = (float*)(ws + 9568256);           // 8*128*4096*4 = 16,777,216
  int*            cnt   = (int*)(ws + 26345472);            // 64 x 64B padded counters

  roipool_kernel<<<dim3(32, 128), 256, 0, stream>>>(x, rois, Apool, cnt);
  gemm_kernel<1><<<512, 256, 0, stream>>>(Apool, W1, part, 25088, 3136,
                                          b1, fc6, cnt);
  gemm_kernel<0><<<512, 256, 0, stream>>>((const __hip_bfloat16*)fc6, W2, part,
                                          4096, 512, nullptr, nullptr, nullptr);
  final_kernel<<<128, 512, 0, stream>>>(part, b2, Wloc, bloc, Wscore, bscore, out);
}

// Round 10
// 253.473 us; speedup vs baseline: 3.0820x; 1.0940x over previous
//
#include <hip/hip_runtime.h>
#include <hip/hip_bf16.h>

// ---------------------------------------------------------------------------
// RoIHead 5-kernel pipeline = R2 champion with ONE safe fusion:
//  K1 roipool            (byte-identical to R2)
//  K2 gemm1 split-K=8    (byte-identical to R2, no tail)
//  K3 reduce0 -> fc6     (byte-identical to R2)
//  K4 gemm2 split-K=8    (byte-identical to R2)
//  K5 reduce1+final fused (reads part directly; validated in R9)
// No new synchronization; R5-R9 showed every added sync mechanism cost more
// than the launch it saved.
// ---------------------------------------------------------------------------

typedef __attribute__((ext_vector_type(8))) short bf16x8;
typedef __attribute__((ext_vector_type(4))) float f32x4;
typedef __attribute__((ext_vector_type(4))) short s16x4;

typedef const __attribute__((address_space(1))) void gvoid;
typedef __attribute__((address_space(3))) void lvoid;
#define GLD_LDS16(gp, lp) __builtin_amdgcn_global_load_lds((gvoid*)(gp), (lvoid*)(lp), 16, 0, 0)

#define WAITV8() { asm volatile("s_waitcnt vmcnt(8)" ::: "memory"); __builtin_amdgcn_sched_barrier(0); }
#define WAITV0() { asm volatile("s_waitcnt vmcnt(0)" ::: "memory"); __builtin_amdgcn_sched_barrier(0); }
#define BAR() { __builtin_amdgcn_sched_barrier(0); __builtin_amdgcn_s_barrier(); __builtin_amdgcn_sched_barrier(0); }

static __device__ __forceinline__ short f2bf(float f) {   // RNE f32->bf16
  unsigned u = __builtin_bit_cast(unsigned, f);
  u += 0x7fffu + ((u >> 16) & 1u);
  return (short)(u >> 16);
}

// ---------------- K1: ROI pool -> A bf16 [128][25088] ----------------
__global__ __launch_bounds__(256) void roipool_kernel(
    const float* __restrict__ x, const float* __restrict__ rois,
    __hip_bfloat16* __restrict__ A) {
  const int cg = blockIdx.x;      // 0..31, 16 channels each
  const int r  = blockIdx.y;      // 0..127
  const float y1 = rois[r*4+0], x1 = rois[r*4+1], y2 = rois[r*4+2], x2 = rois[r*4+3];
  const int h0 = (int)(y1 * 0.0625f);
  const int h1 = (int)(y2 * 0.0625f) + 1;
  const int w0 = (int)(x1 * 0.0625f);
  const int w1 = (int)(x2 * 0.0625f) + 1;
  const int Hh = h1 - h0, Ww = w1 - w0;        // <= 17 each
  const int n = Hh * Ww;                       // <= 289
  __shared__ float tile[16][292];
  const int cl = threadIdx.x >> 4, i = threadIdx.x & 15;
  const int c = cg*16 + cl;
  const float* xc = x + c*1850 + h0*50 + w0;   // x: [512][37][50]
  for (int p = i; p < n; p += 16) {
    int rr = p / Ww, cc = p - rr*Ww;
    tile[cl][p] = xc[rr*50 + cc];
  }
  __syncthreads();
  __hip_bfloat16* Arow = A + (size_t)r*25088 + c*49;
  for (int b = i; b < 49; b += 16) {
    int hb = b / 7, wb = b - hb*7;
    int rs = (hb*Hh)/7,  re = ((hb+1)*Hh + 6)/7;
    int cs = (wb*Ww)/7,  ce = ((wb+1)*Ww + 6)/7;
    float m = -3.402823466e38f;
    for (int rr2 = rs; rr2 < re; ++rr2)
      for (int cc2 = cs; cc2 < ce; ++cc2)
        m = fmaxf(m, tile[cl][rr2*Ww + cc2]);
    Arow[b] = __float2bfloat16(m);
  }
}

// ---------------- K2/K4: MFMA split-K GEMM (R2 body) ----------------
__global__ __launch_bounds__(256) void gemm_kernel(
    const __hip_bfloat16* __restrict__ A,  // [128][K] bf16
    const float* __restrict__ B,           // [K][4096] f32
    float* __restrict__ part,              // [8][128][4096] f32
    int K, int KC) {
  __shared__ short lA[2][8192];    // 2 x 16 KB
  __shared__ float lB[2][4096];    // 2 x 16 KB
  const int t = threadIdx.x;
  const int w = t >> 6, l = t & 63;
  const int bid = blockIdx.x;
  const int s  = bid & 7;          // XCD-locality: same s stays on one XCD
  const int nb = bid >> 3;
  const int kc0 = s * KC;
  const int Arow_bytes = K * 2;

  int aoff[4], boff[4];
#pragma unroll
  for (int p = 0; p < 4; ++p) {
    int o = (p*256 + t) * 16;                     // linear LDS byte offset
    int oa = o ^ (((o >> 7) & 7) << 4);           // inverse A swizzle (involution)
    aoff[p] = (oa >> 7) * Arow_bytes + (oa & 127);
    int ob = o ^ (((o >> 11) & 1) << 6);          // inverse B swizzle (involution)
    boff[p] = (ob >> 8) * 16384 + (ob & 255);
  }
  const int r15 = l & 15, kh = l >> 4;
  const int xa = (r15 & 7) << 4;
  const int aoj0 = r15*128 + ((kh*16) ^ xa);
  const int aoj1 = r15*128 + (((64) + kh*16) ^ xa);
  const int bo0  = ((kh*8)*256 + (w*16 + r15)*4) ^ ((kh & 1) << 6);

  const char* Ak = (const char*)A + kc0*2;
  const char* Bk = (const char*)B + (size_t)kc0*16384 + nb*256;

  f32x4 acc[8] = {};
  const int steps = KC >> 6;
  int cur = 0;

#pragma unroll
  for (int p = 0; p < 4; ++p) {
    GLD_LDS16(Ak + aoff[p], (char*)lA[0] + (p*256 + w*64)*16);
    GLD_LDS16(Bk + boff[p], (char*)lB[0] + (p*256 + w*64)*16);
  }
  Ak += 128; Bk += 64 * 16384;

  for (int st = 0; st < steps; ++st) {
    if (st + 1 < steps) {
      char* dA = (char*)lA[cur ^ 1];
      char* dB = (char*)lB[cur ^ 1];
#pragma unroll
      for (int p = 0; p < 4; ++p) {
        GLD_LDS16(Ak + aoff[p], dA + (p*256 + w*64)*16);
        GLD_LDS16(Bk + boff[p], dB + (p*256 + w*64)*16);
      }
      Ak += 128; Bk += 64 * 16384;
      WAITV8();
    } else {
      WAITV0();
    }
    BAR();
    const char* lAb = (const char*)lA[cur];
    const char* lBb = (const char*)lB[cur];
#pragma unroll
    for (int j = 0; j < 2; ++j) {
      const int ao = j ? aoj1 : aoj0;
      const int bo = (j ? 8192 : 0) + bo0;
      float bf[8];
#pragma unroll
      for (int i2 = 0; i2 < 8; ++i2)
        bf[i2] = *(const float*)(lBb + bo + i2*256);
      bf16x8 bfrag;
#pragma unroll
      for (int i2 = 0; i2 < 8; ++i2) bfrag[i2] = f2bf(bf[i2]);
#pragma unroll
      for (int mf = 0; mf < 8; ++mf) {
        bf16x8 afrag = *(const bf16x8*)(lAb + mf*2048 + ao);
        acc[mf] = __builtin_amdgcn_mfma_f32_16x16x32_bf16(afrag, bfrag, acc[mf], 0, 0, 0);
      }
    }
    BAR();
    cur ^= 1;
  }
  // C/D: col = lane&15, row = (lane>>4)*4 + q
  const int n = nb*64 + w*16 + r15;
  float* prow = part + (size_t)s*524288 + n;
#pragma unroll
  for (int mf = 0; mf < 8; ++mf) {
    int m0 = mf*16 + kh*4;
#pragma unroll
    for (int q = 0; q < 4; ++q)
      prow[(m0 + q)*4096] = acc[mf][q];
  }
}

// ---------------- K3: reduce partials + b1 + relu -> fc6 bf16 ----------------
__global__ __launch_bounds__(256) void reduce_kernel(
    const float* __restrict__ part, const float* __restrict__ bias,
    short* __restrict__ outp) {
  const int idx = (blockIdx.x*256 + threadIdx.x) * 4;   // over 128*4096
  f32x4 sum = {};
#pragma unroll
  for (int s2 = 0; s2 < 8; ++s2)
    sum += *(const f32x4*)(part + (size_t)s2*524288 + idx);
  sum += *(const f32x4*)(bias + (idx & 4095));
  s16x4 o;
#pragma unroll
  for (int q = 0; q < 4; ++q) o[q] = f2bf(fmaxf(sum[q], 0.f));
  *(s16x4*)(outp + idx) = o;
}

// ---------------- K5: reduce partials + b2 + relu -> row; row @ {Wloc,Wscore}
__global__ __launch_bounds__(512) void final_kernel(
    const float* __restrict__ part, const float* __restrict__ b2,
    const float* __restrict__ Wloc, const float* __restrict__ bloc,
    const float* __restrict__ Wscore, const float* __restrict__ bscore,
    float* __restrict__ out) {
  __shared__ float row[4096];
  __shared__ float psum[4][128];
  const int r = blockIdx.x, t = threadIdx.x;
  for (int ci = t; ci < 1024; ci += 512) {
    f32x4 sum = {};
#pragma unroll
    for (int s2 = 0; s2 < 8; ++s2)
      sum += *(const f32x4*)(part + (size_t)s2*524288 + r*4096 + ci*4);
    sum += *(const f32x4*)(b2 + ci*4);
    f32x4 o;
#pragma unroll
    for (int q = 0; q < 4; ++q) o[q] = fmaxf(sum[q], 0.f);
    *(f32x4*)&row[ci*4] = o;
  }
  __syncthreads();
  const int c = t & 127, ks = t >> 7;
  float acc = 0.f;
  if (c < 105) {
    const float* W; int stride, cc;
    if (c < 84) { W = Wloc; stride = 84; cc = c; }
    else        { W = Wscore; stride = 21; cc = c - 84; }
    const int k0 = ks * 1024;
#pragma unroll 4
    for (int k = k0; k < k0 + 1024; ++k)
      acc = fmaf(row[k], W[(size_t)k*stride + cc], acc);
  }
  psum[ks][c] = acc;
  __syncthreads();
  if (ks == 0 && c < 105) {
    float v = psum[0][c] + psum[1][c] + psum[2][c] + psum[3][c];
    if (c < 84) out[(size_t)r*84 + c] = v + bloc[c];
    else        out[10752 + (size_t)r*21 + (c - 84)] = v + bscore[c - 84];
  }
}

// ---------------------------------------------------------------------------
extern "C" void kernel_launch(void* const* d_in, const int* in_sizes, int n_in,
                              void* d_out, int out_size, void* d_ws, size_t ws_size,
                              hipStream_t stream) {
  const float* x      = (const float*)d_in[0];
  const float* rois   = (const float*)d_in[1];
  const float* W1     = (const float*)d_in[2];
  const float* b1     = (const float*)d_in[3];
  const float* W2     = (const float*)d_in[4];
  const float* b2     = (const float*)d_in[5];
  const float* Wloc   = (const float*)d_in[6];
  const float* bloc   = (const float*)d_in[7];
  const float* Wscore = (const float*)d_in[8];
  const float* bscore = (const float*)d_in[9];
  float* out = (float*)d_out;

  char* ws = (char*)d_ws;
  __hip_bfloat16* Apool = (__hip_bfloat16*)(ws);            // 128*25088*2 = 6,422,528
  short*          fc6   = (short*)(ws + 6422528);           // 128*4096*2  = 1,048,576
  float*          part  = (float*)(ws + 9568256);           // 8*128*4096*4 = 16,777,216

  roipool_kernel<<<dim3(32, 128), 256, 0, stream>>>(x, rois, Apool);
  gemm_kernel<<<512, 256, 0, stream>>>(Apool, W1, part, 25088, 3136);
  reduce_kernel<<<512, 256, 0, stream>>>(part, b1, fc6);
  gemm_kernel<<<512, 256, 0, stream>>>((const __hip_bfloat16*)fc6, W2, part, 4096, 512);
  final_kernel<<<128, 512, 0, stream>>>(part, b2, Wloc, bloc, Wscore, bscore, out);
}